// Round 2
// baseline (5930.524 us; speedup 1.0000x reference)
//
#include <hip/hip_runtime.h>
#include <cstdint>
#include <cstddef>

#define N_NODES_C 262144
#define N_EDGES_C 524288
#define N_GRAPHS_C 8192
#define BN_EPS_C 1e-5f

// ---------------------------------------------------------------- copy (flat float4) — layer 0 only
__global__ __launch_bounds__(256) void copy_f4_kernel(const float4* __restrict__ in,
                                                      float4* __restrict__ out, int n4) {
  int i = blockIdx.x * 256 + threadIdx.x;
  if (i < n4) out[i] = in[i];
}

// ---------------------------------------------------------------- edge scatter-add
__global__ __launch_bounds__(256) void scatter77_kernel(const float* __restrict__ h,
                                                        const int* __restrict__ src,
                                                        const int* __restrict__ dst,
                                                        float* __restrict__ agg) {
  int idx = blockIdx.x * 256 + threadIdx.x;
  if (idx >= N_EDGES_C * 77) return;
  int e = idx / 77;
  int f = idx - e * 77;
  float v = h[(size_t)src[e] * 77 + f];
  atomicAdd(&agg[(size_t)dst[e] * 77 + f], v);
}

__global__ __launch_bounds__(256) void scatter128_kernel(const float4* __restrict__ h4,
                                                         const int* __restrict__ src,
                                                         const int* __restrict__ dst,
                                                         float* __restrict__ agg) {
  int idx = blockIdx.x * 256 + threadIdx.x;  // exactly N_EDGES*32 threads
  int e = idx >> 5, q = idx & 31;
  int s = src[e], d = dst[e];
  float4 v = h4[(size_t)s * 32 + q];
  float* p = agg + (size_t)d * 128 + q * 4;
  atomicAdd(p + 0, v.x);
  atomicAdd(p + 1, v.y);
  atomicAdd(p + 2, v.z);
  atomicAdd(p + 3, v.w);
}

// ---------------------------------------------------------------- GEMM + bias + relu (+BN stats)
// C[N,128] = relu(A[N,FIN] @ W[FIN,128] + bias). 64-row tile per block, 256 threads.
// A tile fully staged in LDS BEFORE any store -> in-place (C==A) safe for FIN==128.
template <int FIN, bool STATS>
__global__ __launch_bounds__(256, 4) void gemm_kernel(const float* __restrict__ A,
                                                      const float* __restrict__ W,
                                                      const float* __restrict__ bias,
                                                      float* __restrict__ C,
                                                      float* __restrict__ stats) {
  constexpr int PAD = (FIN % 2 == 0) ? FIN + 1 : FIN;  // odd stride -> conflict-free row broadcast
  __shared__ float As[64 * PAD];
  __shared__ float bsum[128];
  __shared__ float bsq[128];

  const int t = threadIdx.x;
  const size_t rowBase = (size_t)blockIdx.x * 64;

  // ---- stage A tile
  if constexpr (FIN % 4 == 0) {
    const float4* A4 = (const float4*)(A + rowBase * FIN);
    constexpr int R4 = FIN / 4;
    for (int j = t; j < 64 * R4; j += 256) {
      int r = j / R4, c4 = j - r * R4;
      float4 v = A4[j];
      float* d = &As[r * PAD + c4 * 4];
      d[0] = v.x; d[1] = v.y; d[2] = v.z; d[3] = v.w;
    }
  } else {
    const float* Ab = A + rowBase * FIN;
    for (int j = t; j < 64 * FIN; j += 256) {
      int r = j / FIN, c = j - r * FIN;
      As[r * PAD + c] = Ab[j];
    }
  }
  __syncthreads();

  const int tr = t >> 4;     // 0..15  -> rows tr, tr+16, tr+32, tr+48
  const int tc = t & 15;     // 0..15  -> cols [tc*4, tc*4+3] and [64+tc*4, 64+tc*4+3]

  float4 acc0[4] = {};
  float4 acc1[4] = {};
  const float4* W4 = (const float4*)W;

#pragma unroll 4
  for (int k = 0; k < FIN; ++k) {
    float4 w0 = W4[k * 32 + tc];
    float4 w1 = W4[k * 32 + 16 + tc];
    float a[4];
    a[0] = As[(tr + 0) * PAD + k];
    a[1] = As[(tr + 16) * PAD + k];
    a[2] = As[(tr + 32) * PAD + k];
    a[3] = As[(tr + 48) * PAD + k];
#pragma unroll
    for (int i = 0; i < 4; ++i) {
      acc0[i].x += a[i] * w0.x; acc0[i].y += a[i] * w0.y;
      acc0[i].z += a[i] * w0.z; acc0[i].w += a[i] * w0.w;
      acc1[i].x += a[i] * w1.x; acc1[i].y += a[i] * w1.y;
      acc1[i].z += a[i] * w1.z; acc1[i].w += a[i] * w1.w;
    }
  }

  const float4 b0 = ((const float4*)bias)[tc];
  const float4 b1 = ((const float4*)bias)[16 + tc];

  float4 s0 = {}, s1 = {}, q0 = {}, q1 = {};

#pragma unroll
  for (int i = 0; i < 4; ++i) {
    size_t r = rowBase + tr + 16 * i;
    float4 v0, v1;
    v0.x = fmaxf(acc0[i].x + b0.x, 0.f);
    v0.y = fmaxf(acc0[i].y + b0.y, 0.f);
    v0.z = fmaxf(acc0[i].z + b0.z, 0.f);
    v0.w = fmaxf(acc0[i].w + b0.w, 0.f);
    v1.x = fmaxf(acc1[i].x + b1.x, 0.f);
    v1.y = fmaxf(acc1[i].y + b1.y, 0.f);
    v1.z = fmaxf(acc1[i].z + b1.z, 0.f);
    v1.w = fmaxf(acc1[i].w + b1.w, 0.f);
    ((float4*)C)[r * 32 + tc] = v0;
    ((float4*)C)[r * 32 + 16 + tc] = v1;
    if constexpr (STATS) {
      s0.x += v0.x; s0.y += v0.y; s0.z += v0.z; s0.w += v0.w;
      s1.x += v1.x; s1.y += v1.y; s1.z += v1.z; s1.w += v1.w;
      q0.x += v0.x * v0.x; q0.y += v0.y * v0.y; q0.z += v0.z * v0.z; q0.w += v0.w * v0.w;
      q1.x += v1.x * v1.x; q1.y += v1.y * v1.y; q1.z += v1.z * v1.z; q1.w += v1.w * v1.w;
    }
  }

  if constexpr (STATS) {
    if (t < 128) { bsum[t] = 0.f; bsq[t] = 0.f; }
    __syncthreads();
    int c0 = tc * 4, c1 = 64 + tc * 4;
    atomicAdd(&bsum[c0 + 0], s0.x); atomicAdd(&bsum[c0 + 1], s0.y);
    atomicAdd(&bsum[c0 + 2], s0.z); atomicAdd(&bsum[c0 + 3], s0.w);
    atomicAdd(&bsum[c1 + 0], s1.x); atomicAdd(&bsum[c1 + 1], s1.y);
    atomicAdd(&bsum[c1 + 2], s1.z); atomicAdd(&bsum[c1 + 3], s1.w);
    atomicAdd(&bsq[c0 + 0], q0.x); atomicAdd(&bsq[c0 + 1], q0.y);
    atomicAdd(&bsq[c0 + 2], q0.z); atomicAdd(&bsq[c0 + 3], q0.w);
    atomicAdd(&bsq[c1 + 0], q1.x); atomicAdd(&bsq[c1 + 1], q1.y);
    atomicAdd(&bsq[c1 + 2], q1.z); atomicAdd(&bsq[c1 + 3], q1.w);
    __syncthreads();
    if (t < 128) {
      atomicAdd(&stats[t], bsum[t]);
      atomicAdd(&stats[128 + t], bsq[t]);
    }
  }
}

// ---------------------------------------------------------------- BN apply + segment_max pool (+AGG init)
// one block per graph (32 consecutive rows). Writes normalized h back, pooled max to out,
// and (WRITE_AGG) duplicates normalized h into agg as the identity term for the next
// layer's scatter-add — this replaces a whole copy kernel (saves a 134 MB read/layer).
template <bool WRITE_AGG>
__global__ __launch_bounds__(256) void bn_pool_kernel(float* __restrict__ h,
                                                      float* __restrict__ agg,
                                                      const float* __restrict__ stats,
                                                      const float* __restrict__ gamma,
                                                      const float* __restrict__ beta,
                                                      float* __restrict__ out, int layer) {
  __shared__ float red[256];
  const int g = blockIdx.x;
  const int t = threadIdx.x;
  const int f = t & 127, half = t >> 7;

  const float inv_n = 1.0f / (float)N_NODES_C;
  float mean = stats[f] * inv_n;
  float var = stats[128 + f] * inv_n - mean * mean;
  float sc = gamma[layer * 128 + f] * rsqrtf(var + BN_EPS_C);
  float sh = beta[layer * 128 + f] - mean * sc;

  float m = -3.4e38f;
  size_t base = ((size_t)g * 32 + half * 16) * 128 + f;
#pragma unroll
  for (int r = 0; r < 16; ++r) {
    float v = h[base + (size_t)r * 128];
    v = v * sc + sh;
    h[base + (size_t)r * 128] = v;
    if constexpr (WRITE_AGG) agg[base + (size_t)r * 128] = v;
    m = fmaxf(m, v);
  }
  red[t] = m;
  __syncthreads();
  if (t < 128) out[(size_t)g * 640 + layer * 128 + f] = fmaxf(red[t], red[t + 128]);
}

// ---------------------------------------------------------------- launch
extern "C" void kernel_launch(void* const* d_in, const int* in_sizes, int n_in,
                              void* d_out, int out_size, void* d_ws, size_t ws_size,
                              hipStream_t stream) {
  const float* x = (const float*)d_in[0];
  const int* ei = (const int*)d_in[1];
  const int* src = ei;
  const int* dst = ei + N_EDGES_C;
  const float* w0a = (const float*)d_in[3];
  const float* b0a = (const float*)d_in[4];
  const float* w0b = (const float*)d_in[5];
  const float* b0b = (const float*)d_in[6];
  const float* wa = (const float*)d_in[7];
  const float* ba = (const float*)d_in[8];
  const float* wb = (const float*)d_in[9];
  const float* bb = (const float*)d_in[10];
  const float* gamma = (const float*)d_in[11];
  const float* beta = (const float*)d_in[12];
  float* out = (float*)d_out;

  const size_t NNf = (size_t)N_NODES_C * 128;
  float* ws = (float*)d_ws;
  const bool big = ws_size >= (3 * NNf + 256) * sizeof(float);
  float* H = ws;
  float* AGG = ws + NNf;
  float* TMP = big ? ws + 2 * NNf : nullptr;   // 2-buf mode: GEMM1 runs in-place
  float* STATS = big ? ws + 3 * NNf : ws + 2 * NNf;

  // ---------- layer 0 (FIN=77)
  {
    const int n4 = (N_NODES_C * 77) / 4;                       // 5046272
    copy_f4_kernel<<<n4 / 256, 256, 0, stream>>>((const float4*)x, (float4*)AGG, n4);
    scatter77_kernel<<<(N_EDGES_C * 77) / 256, 256, 0, stream>>>(x, src, dst, AGG);
    float* g1o = big ? TMP : H;
    gemm_kernel<77, false><<<N_NODES_C / 64, 256, 0, stream>>>(AGG, w0a, b0a, g1o, nullptr);
    hipMemsetAsync(STATS, 0, 256 * sizeof(float), stream);
    gemm_kernel<128, true><<<N_NODES_C / 64, 256, 0, stream>>>(g1o, w0b, b0b, H, STATS);
    bn_pool_kernel<true><<<N_GRAPHS_C, 256, 0, stream>>>(H, AGG, STATS, gamma, beta, out, 0);
  }

  // ---------- layers 1..4 (FIN=128); AGG comes pre-initialized (= normalized h) from bn_pool
  for (int i = 1; i < 5; ++i) {
    scatter128_kernel<<<(N_EDGES_C * 32) / 256, 256, 0, stream>>>((const float4*)H, src, dst, AGG);
    float* g1o = big ? TMP : AGG;                              // 2-buf: in-place AGG->AGG (safe: A staged first)
    gemm_kernel<128, false><<<N_NODES_C / 64, 256, 0, stream>>>(AGG, wa + (size_t)(i - 1) * 128 * 128,
                                                                ba + (size_t)(i - 1) * 128, g1o, nullptr);
    hipMemsetAsync(STATS, 0, 256 * sizeof(float), stream);
    gemm_kernel<128, true><<<N_NODES_C / 64, 256, 0, stream>>>(g1o, wb + (size_t)(i - 1) * 128 * 128,
                                                               bb + (size_t)(i - 1) * 128, H, STATS);
    if (i < 4) {
      bn_pool_kernel<true><<<N_GRAPHS_C, 256, 0, stream>>>(H, AGG, STATS, gamma, beta, out, i);
    } else {
      bn_pool_kernel<false><<<N_GRAPHS_C, 256, 0, stream>>>(H, nullptr, STATS, gamma, beta, out, i);
    }
  }
}

// Round 3
// 2541.766 us; speedup vs baseline: 2.3332x; 2.3332x over previous
//
#include <hip/hip_runtime.h>
#include <cstdint>
#include <cstddef>

#define N_NODES_C 262144
#define N_EDGES_C 524288
#define N_GRAPHS_C 8192
#define BN_EPS_C 1e-5f

// ================================================================ CSR build (once per launch)
// counting-sort edges by dst: cnt -> exclusive scan (2-level) -> bucket scatter of src ids.

__global__ __launch_bounds__(256) void hist_kernel(const int* __restrict__ dst, int* __restrict__ cnt) {
  int e = blockIdx.x * 256 + threadIdx.x;
  if (e < N_EDGES_C) atomicAdd(&cnt[dst[e]], 1);
}

// 256 blocks x 1024 elements: per-block exclusive scan, block totals to bsums
__global__ __launch_bounds__(256) void scanA_kernel(const int* __restrict__ cnt,
                                                    int* __restrict__ rs, int* __restrict__ bsums) {
  __shared__ int lds[256];
  const int b = blockIdx.x, t = threadIdx.x;
  int4 v = ((const int4*)(cnt + b * 1024))[t];
  lds[t] = v.x + v.y + v.z + v.w;
  __syncthreads();
  for (int off = 1; off < 256; off <<= 1) {
    int add = (t >= off) ? lds[t - off] : 0;
    __syncthreads();
    lds[t] += add;
    __syncthreads();
  }
  int excl = (t > 0) ? lds[t - 1] : 0;
  if (t == 255) bsums[b] = lds[255];
  int4 o;
  o.x = excl; o.y = excl + v.x; o.z = excl + v.x + v.y; o.w = excl + v.x + v.y + v.z;
  ((int4*)(rs + b * 1024))[t] = o;
}

__global__ __launch_bounds__(256) void scanB_kernel(int* __restrict__ bsums) {
  __shared__ int lds[256];
  const int t = threadIdx.x;
  lds[t] = bsums[t];
  __syncthreads();
  for (int off = 1; off < 256; off <<= 1) {
    int add = (t >= off) ? lds[t - off] : 0;
    __syncthreads();
    lds[t] += add;
    __syncthreads();
  }
  bsums[t] = (t > 0) ? lds[t - 1] : 0;
}

__global__ __launch_bounds__(256) void scanC_kernel(int* __restrict__ rs, int* __restrict__ cursor,
                                                    const int* __restrict__ bsums) {
  int i = blockIdx.x * 256 + threadIdx.x;  // N_NODES threads
  int v = rs[i] + bsums[i >> 10];
  rs[i] = v;
  cursor[i] = v;
  if (i == 0) rs[N_NODES_C] = N_EDGES_C;
}

__global__ __launch_bounds__(256) void edge_bucket_kernel(const int* __restrict__ src,
                                                          const int* __restrict__ dst,
                                                          int* __restrict__ cursor,
                                                          int* __restrict__ ebuf) {
  int e = blockIdx.x * 256 + threadIdx.x;
  if (e >= N_EDGES_C) return;
  int pos = atomicAdd(&cursor[dst[e]], 1);
  ebuf[pos] = src[e];
}

// ================================================================ gather aggregation (no atomics)
// agg[n] = h[n] + sum_{incoming e} h[src(e)]. 32 threads (half-wave) per node.

__global__ __launch_bounds__(256) void agg128_kernel(const float4* __restrict__ h4,
                                                     const int* __restrict__ rs,
                                                     const int* __restrict__ ebuf,
                                                     float4* __restrict__ agg4) {
  int idx = blockIdx.x * 256 + threadIdx.x;  // N_NODES*32 threads
  int n = idx >> 5, q = idx & 31;
  int s = rs[n], e = rs[n + 1];
  float4 v = h4[(size_t)n * 32 + q];
  for (int i = s; i < e; ++i) {
    int srcn = ebuf[i];
    float4 u = h4[(size_t)srcn * 32 + q];
    v.x += u.x; v.y += u.y; v.z += u.z; v.w += u.w;
  }
  agg4[(size_t)n * 32 + q] = v;
}

__global__ __launch_bounds__(256) void agg77_kernel(const float* __restrict__ x,
                                                    const int* __restrict__ rs,
                                                    const int* __restrict__ ebuf,
                                                    float* __restrict__ agg) {
  int idx = blockIdx.x * 256 + threadIdx.x;  // N_NODES*32 threads
  int n = idx >> 5, q = idx & 31;
  int s = rs[n], e = rs[n + 1];
  float v0 = 0.f, v1 = 0.f, v2 = 0.f;
  const size_t nb = (size_t)n * 77;
  v0 = x[nb + q];
  if (q + 32 < 77) v1 = x[nb + q + 32];
  if (q + 64 < 77) v2 = x[nb + q + 64];
  for (int i = s; i < e; ++i) {
    const size_t sb = (size_t)ebuf[i] * 77;
    v0 += x[sb + q];
    if (q + 32 < 77) v1 += x[sb + q + 32];
    if (q + 64 < 77) v2 += x[sb + q + 64];
  }
  agg[nb + q] = v0;
  if (q + 32 < 77) agg[nb + q + 32] = v1;
  if (q + 64 < 77) agg[nb + q + 64] = v2;
}

// ================================================================ GEMM + bias + relu (+BN stats)
// C[N,128] = relu(A[N,FIN] @ W[FIN,128] + bias). 64-row tile per block, 256 threads.
// A tile fully staged in LDS BEFORE any store -> in-place (C==A) safe for FIN==128.
template <int FIN, bool STATS>
__global__ __launch_bounds__(256, 4) void gemm_kernel(const float* __restrict__ A,
                                                      const float* __restrict__ W,
                                                      const float* __restrict__ bias,
                                                      float* __restrict__ C,
                                                      float* __restrict__ stats) {
  constexpr int PAD = (FIN % 2 == 0) ? FIN + 1 : FIN;  // odd stride -> conflict-free row broadcast
  __shared__ float As[64 * PAD];
  __shared__ float bsum[128];
  __shared__ float bsq[128];

  const int t = threadIdx.x;
  const size_t rowBase = (size_t)blockIdx.x * 64;

  // ---- stage A tile
  if constexpr (FIN % 4 == 0) {
    const float4* A4 = (const float4*)(A + rowBase * FIN);
    constexpr int R4 = FIN / 4;
    for (int j = t; j < 64 * R4; j += 256) {
      int r = j / R4, c4 = j - r * R4;
      float4 v = A4[j];
      float* d = &As[r * PAD + c4 * 4];
      d[0] = v.x; d[1] = v.y; d[2] = v.z; d[3] = v.w;
    }
  } else {
    const float* Ab = A + rowBase * FIN;
    for (int j = t; j < 64 * FIN; j += 256) {
      int r = j / FIN, c = j - r * FIN;
      As[r * PAD + c] = Ab[j];
    }
  }
  __syncthreads();

  const int tr = t >> 4;     // 0..15  -> rows tr, tr+16, tr+32, tr+48
  const int tc = t & 15;     // 0..15  -> cols [tc*4, tc*4+3] and [64+tc*4, 64+tc*4+3]

  float4 acc0[4] = {};
  float4 acc1[4] = {};
  const float4* W4 = (const float4*)W;

#pragma unroll 4
  for (int k = 0; k < FIN; ++k) {
    float4 w0 = W4[k * 32 + tc];
    float4 w1 = W4[k * 32 + 16 + tc];
    float a[4];
    a[0] = As[(tr + 0) * PAD + k];
    a[1] = As[(tr + 16) * PAD + k];
    a[2] = As[(tr + 32) * PAD + k];
    a[3] = As[(tr + 48) * PAD + k];
#pragma unroll
    for (int i = 0; i < 4; ++i) {
      acc0[i].x += a[i] * w0.x; acc0[i].y += a[i] * w0.y;
      acc0[i].z += a[i] * w0.z; acc0[i].w += a[i] * w0.w;
      acc1[i].x += a[i] * w1.x; acc1[i].y += a[i] * w1.y;
      acc1[i].z += a[i] * w1.z; acc1[i].w += a[i] * w1.w;
    }
  }

  const float4 b0 = ((const float4*)bias)[tc];
  const float4 b1 = ((const float4*)bias)[16 + tc];

  float4 s0 = {}, s1 = {}, q0 = {}, q1 = {};

#pragma unroll
  for (int i = 0; i < 4; ++i) {
    size_t r = rowBase + tr + 16 * i;
    float4 v0, v1;
    v0.x = fmaxf(acc0[i].x + b0.x, 0.f);
    v0.y = fmaxf(acc0[i].y + b0.y, 0.f);
    v0.z = fmaxf(acc0[i].z + b0.z, 0.f);
    v0.w = fmaxf(acc0[i].w + b0.w, 0.f);
    v1.x = fmaxf(acc1[i].x + b1.x, 0.f);
    v1.y = fmaxf(acc1[i].y + b1.y, 0.f);
    v1.z = fmaxf(acc1[i].z + b1.z, 0.f);
    v1.w = fmaxf(acc1[i].w + b1.w, 0.f);
    ((float4*)C)[r * 32 + tc] = v0;
    ((float4*)C)[r * 32 + 16 + tc] = v1;
    if constexpr (STATS) {
      s0.x += v0.x; s0.y += v0.y; s0.z += v0.z; s0.w += v0.w;
      s1.x += v1.x; s1.y += v1.y; s1.z += v1.z; s1.w += v1.w;
      q0.x += v0.x * v0.x; q0.y += v0.y * v0.y; q0.z += v0.z * v0.z; q0.w += v0.w * v0.w;
      q1.x += v1.x * v1.x; q1.y += v1.y * v1.y; q1.z += v1.z * v1.z; q1.w += v1.w * v1.w;
    }
  }

  if constexpr (STATS) {
    if (t < 128) { bsum[t] = 0.f; bsq[t] = 0.f; }
    __syncthreads();
    int c0 = tc * 4, c1 = 64 + tc * 4;
    atomicAdd(&bsum[c0 + 0], s0.x); atomicAdd(&bsum[c0 + 1], s0.y);
    atomicAdd(&bsum[c0 + 2], s0.z); atomicAdd(&bsum[c0 + 3], s0.w);
    atomicAdd(&bsum[c1 + 0], s1.x); atomicAdd(&bsum[c1 + 1], s1.y);
    atomicAdd(&bsum[c1 + 2], s1.z); atomicAdd(&bsum[c1 + 3], s1.w);
    atomicAdd(&bsq[c0 + 0], q0.x); atomicAdd(&bsq[c0 + 1], q0.y);
    atomicAdd(&bsq[c0 + 2], q0.z); atomicAdd(&bsq[c0 + 3], q0.w);
    atomicAdd(&bsq[c1 + 0], q1.x); atomicAdd(&bsq[c1 + 1], q1.y);
    atomicAdd(&bsq[c1 + 2], q1.z); atomicAdd(&bsq[c1 + 3], q1.w);
    __syncthreads();
    if (t < 128) {
      atomicAdd(&stats[t], bsum[t]);
      atomicAdd(&stats[128 + t], bsq[t]);
    }
  }
}

// ================================================================ BN apply + segment_max pool
__global__ __launch_bounds__(256) void bn_pool_kernel(float* __restrict__ h,
                                                      const float* __restrict__ stats,
                                                      const float* __restrict__ gamma,
                                                      const float* __restrict__ beta,
                                                      float* __restrict__ out, int layer) {
  __shared__ float red[256];
  const int g = blockIdx.x;
  const int t = threadIdx.x;
  const int f = t & 127, half = t >> 7;

  const float inv_n = 1.0f / (float)N_NODES_C;
  float mean = stats[f] * inv_n;
  float var = stats[128 + f] * inv_n - mean * mean;
  float sc = gamma[layer * 128 + f] * rsqrtf(var + BN_EPS_C);
  float sh = beta[layer * 128 + f] - mean * sc;

  float m = -3.4e38f;
  size_t base = ((size_t)g * 32 + half * 16) * 128 + f;
#pragma unroll
  for (int r = 0; r < 16; ++r) {
    float v = h[base + (size_t)r * 128];
    v = v * sc + sh;
    h[base + (size_t)r * 128] = v;
    m = fmaxf(m, v);
  }
  red[t] = m;
  __syncthreads();
  if (t < 128) out[(size_t)g * 640 + layer * 128 + f] = fmaxf(red[t], red[t + 128]);
}

// ================================================================ launch
extern "C" void kernel_launch(void* const* d_in, const int* in_sizes, int n_in,
                              void* d_out, int out_size, void* d_ws, size_t ws_size,
                              hipStream_t stream) {
  const float* x = (const float*)d_in[0];
  const int* ei = (const int*)d_in[1];
  const int* src = ei;
  const int* dst = ei + N_EDGES_C;
  const float* w0a = (const float*)d_in[3];
  const float* b0a = (const float*)d_in[4];
  const float* w0b = (const float*)d_in[5];
  const float* b0b = (const float*)d_in[6];
  const float* wa = (const float*)d_in[7];
  const float* ba = (const float*)d_in[8];
  const float* wb = (const float*)d_in[9];
  const float* bb = (const float*)d_in[10];
  const float* gamma = (const float*)d_in[11];
  const float* beta = (const float*)d_in[12];
  float* out = (float*)d_out;

  const size_t NNf = (size_t)N_NODES_C * 128;
  const size_t csr_words = (size_t)N_NODES_C /*cnt*/ + (N_NODES_C + 2) /*rowstart*/ +
                           N_NODES_C /*cursor*/ + 256 /*bsums*/ + N_EDGES_C /*ebuf*/;
  float* ws = (float*)d_ws;
  const bool big = ws_size >= (3 * NNf + 256 + csr_words) * sizeof(float);
  float* H = ws;
  float* AGG = ws + NNf;
  float* TMP = big ? ws + 2 * NNf : nullptr;   // 2-buf mode: GEMM1 runs in-place
  float* STATS = big ? ws + 3 * NNf : ws + 2 * NNf;
  int* cnt = (int*)(STATS + 256);
  int* rowstart = cnt + N_NODES_C;            // N_NODES+2 entries
  int* cursor = rowstart + N_NODES_C + 2;
  int* bsums = cursor + N_NODES_C;
  int* ebuf = bsums + 256;

  // ---------- CSR build (edge_index fixed per launch)
  hipMemsetAsync(cnt, 0, N_NODES_C * sizeof(int), stream);
  hist_kernel<<<N_EDGES_C / 256, 256, 0, stream>>>(dst, cnt);
  scanA_kernel<<<256, 256, 0, stream>>>(cnt, rowstart, bsums);
  scanB_kernel<<<1, 256, 0, stream>>>(bsums);
  scanC_kernel<<<N_NODES_C / 256, 256, 0, stream>>>(rowstart, cursor, bsums);
  edge_bucket_kernel<<<N_EDGES_C / 256, 256, 0, stream>>>(src, dst, cursor, ebuf);

  // ---------- layer 0 (FIN=77)
  {
    agg77_kernel<<<(N_NODES_C * 32) / 256, 256, 0, stream>>>(x, rowstart, ebuf, AGG);
    float* g1o = big ? TMP : H;
    gemm_kernel<77, false><<<N_NODES_C / 64, 256, 0, stream>>>(AGG, w0a, b0a, g1o, nullptr);
    hipMemsetAsync(STATS, 0, 256 * sizeof(float), stream);
    gemm_kernel<128, true><<<N_NODES_C / 64, 256, 0, stream>>>(g1o, w0b, b0b, H, STATS);
    bn_pool_kernel<<<N_GRAPHS_C, 256, 0, stream>>>(H, STATS, gamma, beta, out, 0);
  }

  // ---------- layers 1..4 (FIN=128)
  for (int i = 1; i < 5; ++i) {
    agg128_kernel<<<(N_NODES_C * 32) / 256, 256, 0, stream>>>((const float4*)H, rowstart, ebuf,
                                                              (float4*)AGG);
    float* g1o = big ? TMP : AGG;                              // 2-buf: in-place AGG->AGG (safe: A staged first)
    gemm_kernel<128, false><<<N_NODES_C / 64, 256, 0, stream>>>(AGG, wa + (size_t)(i - 1) * 128 * 128,
                                                                ba + (size_t)(i - 1) * 128, g1o, nullptr);
    hipMemsetAsync(STATS, 0, 256 * sizeof(float), stream);
    gemm_kernel<128, true><<<N_NODES_C / 64, 256, 0, stream>>>(g1o, wb + (size_t)(i - 1) * 128 * 128,
                                                               bb + (size_t)(i - 1) * 128, H, STATS);
    bn_pool_kernel<<<N_GRAPHS_C, 256, 0, stream>>>(H, STATS, gamma, beta, out, i);
  }
}

// Round 4
// 1940.908 us; speedup vs baseline: 3.0555x; 1.3096x over previous
//
#include <hip/hip_runtime.h>
#include <cstdint>
#include <cstddef>

#define N_NODES_C 262144
#define N_EDGES_C 524288
#define N_GRAPHS_C 8192
#define BN_EPS_C 1e-5f

typedef short short8 __attribute__((ext_vector_type(8)));
typedef float f32x4 __attribute__((ext_vector_type(4)));

__device__ __forceinline__ unsigned short f2bf(float f) {
  unsigned int u = __float_as_uint(f);
  u += 0x7fffu + ((u >> 16) & 1u);   // RN-even
  return (unsigned short)(u >> 16);
}
__device__ __forceinline__ float bf2f(unsigned short h) {
  return __uint_as_float(((unsigned int)h) << 16);
}

// ================================================================ CSR build (once per launch)
__global__ __launch_bounds__(256) void hist_kernel(const int* __restrict__ dst, int* __restrict__ cnt) {
  int e = blockIdx.x * 256 + threadIdx.x;
  if (e < N_EDGES_C) atomicAdd(&cnt[dst[e]], 1);
}

__global__ __launch_bounds__(256) void scanA_kernel(const int* __restrict__ cnt,
                                                    int* __restrict__ rs, int* __restrict__ bsums) {
  __shared__ int lds[256];
  const int b = blockIdx.x, t = threadIdx.x;
  int4 v = ((const int4*)(cnt + b * 1024))[t];
  lds[t] = v.x + v.y + v.z + v.w;
  __syncthreads();
  for (int off = 1; off < 256; off <<= 1) {
    int add = (t >= off) ? lds[t - off] : 0;
    __syncthreads();
    lds[t] += add;
    __syncthreads();
  }
  int excl = (t > 0) ? lds[t - 1] : 0;
  if (t == 255) bsums[b] = lds[255];
  int4 o;
  o.x = excl; o.y = excl + v.x; o.z = excl + v.x + v.y; o.w = excl + v.x + v.y + v.z;
  ((int4*)(rs + b * 1024))[t] = o;
}

__global__ __launch_bounds__(256) void scanB_kernel(int* __restrict__ bsums) {
  __shared__ int lds[256];
  const int t = threadIdx.x;
  lds[t] = bsums[t];
  __syncthreads();
  for (int off = 1; off < 256; off <<= 1) {
    int add = (t >= off) ? lds[t - off] : 0;
    __syncthreads();
    lds[t] += add;
    __syncthreads();
  }
  bsums[t] = (t > 0) ? lds[t - 1] : 0;
}

__global__ __launch_bounds__(256) void scanC_kernel(int* __restrict__ rs, int* __restrict__ cursor,
                                                    const int* __restrict__ bsums) {
  int i = blockIdx.x * 256 + threadIdx.x;
  int v = rs[i] + bsums[i >> 10];
  rs[i] = v;
  cursor[i] = v;
  if (i == 0) rs[N_NODES_C] = N_EDGES_C;
}

__global__ __launch_bounds__(256) void edge_bucket_kernel(const int* __restrict__ src,
                                                          const int* __restrict__ dst,
                                                          int* __restrict__ cursor,
                                                          int* __restrict__ ebuf) {
  int e = blockIdx.x * 256 + threadIdx.x;
  if (e >= N_EDGES_C) return;
  int pos = atomicAdd(&cursor[dst[e]], 1);
  ebuf[pos] = src[e];
}

// ================================================================ gather aggregation
__global__ __launch_bounds__(256) void agg128_kernel(const float4* __restrict__ h4,
                                                     const int* __restrict__ rs,
                                                     const int* __restrict__ ebuf,
                                                     float4* __restrict__ agg4) {
  int idx = blockIdx.x * 256 + threadIdx.x;
  int n = idx >> 5, q = idx & 31;
  int s = rs[n], e = rs[n + 1];
  float4 v = h4[(size_t)n * 32 + q];
  for (int i = s; i < e; ++i) {
    int srcn = ebuf[i];
    float4 u = h4[(size_t)srcn * 32 + q];
    v.x += u.x; v.y += u.y; v.z += u.z; v.w += u.w;
  }
  agg4[(size_t)n * 32 + q] = v;
}

// layer-0 gather: reads x[N,77], writes zero-padded agg[N,128]
__global__ __launch_bounds__(256) void agg77_kernel(const float* __restrict__ x,
                                                    const int* __restrict__ rs,
                                                    const int* __restrict__ ebuf,
                                                    float* __restrict__ agg) {
  int idx = blockIdx.x * 256 + threadIdx.x;
  int n = idx >> 5, q = idx & 31;
  int s = rs[n], e = rs[n + 1];
  const size_t nb = (size_t)n * 77;
  float v0 = x[nb + q];
  float v1 = x[nb + q + 32];                    // q+32 <= 63 < 77 always valid
  float v2 = (q < 13) ? x[nb + q + 64] : 0.f;   // q+64 < 77 iff q < 13
  for (int i = s; i < e; ++i) {
    const size_t sb = (size_t)ebuf[i] * 77;
    v0 += x[sb + q];
    v1 += x[sb + q + 32];
    if (q < 13) v2 += x[sb + q + 64];
  }
  const size_t ob = (size_t)n * 128;
  agg[ob + q] = v0;
  agg[ob + q + 32] = v1;
  agg[ob + q + 64] = (q < 13) ? v2 : 0.f;
  agg[ob + q + 96] = 0.f;
}

// ================================================================ weight split + frag-pack (once)
// 10 matrices, each logical [K=128][128] (w0a zero-padded past k=77).
// Packed layout: [mat][ct(8)][ks(4)][lane(64)][j(8)]  (bf16 bits as ushort)
// frag element: W[k = ks*32 + (lane>>4)*8 + j][c = ct*16 + (lane&15)]
__global__ __launch_bounds__(256) void wsplit_kernel(const float* __restrict__ w0a,
                                                     const float* __restrict__ w0b,
                                                     const float* __restrict__ wa,
                                                     const float* __restrict__ wb,
                                                     unsigned short* __restrict__ Whi,
                                                     unsigned short* __restrict__ Wlo) {
  int tid = blockIdx.x * 256 + threadIdx.x;      // 20480 total
  int mat = tid >> 11;
  int rem = tid & 2047;
  int ct = rem >> 8;
  int ks = (rem >> 6) & 3;
  int lane = rem & 63;
  const int c = ct * 16 + (lane & 15);
  const size_t base = (size_t)mat * 16384 + (size_t)((ct * 4 + ks) * 64 + lane) * 8;
#pragma unroll
  for (int j = 0; j < 8; ++j) {
    int k = ks * 32 + ((lane >> 4) << 3) + j;
    float w;
    if (mat == 0)      w = (k < 77) ? w0a[k * 128 + c] : 0.f;
    else if (mat == 1) w = w0b[k * 128 + c];
    else if (mat < 6)  w = wa[(size_t)(mat - 2) * 16384 + k * 128 + c];
    else               w = wb[(size_t)(mat - 6) * 16384 + k * 128 + c];
    unsigned short h = f2bf(w);
    Whi[base + j] = h;
    Wlo[base + j] = f2bf(w - bf2f(h));
  }
}

// ================================================================ MFMA GEMM (bf16 hi/lo x3)
// C[N,128] = relu(A[N,128] @ W + bias). 256 thr = 4 waves, 16 rows/wave, 64 rows/block.
// In-place safe: each wave reads & writes only its own 16-row strip.
template <bool STATS>
__global__ __launch_bounds__(256) void gemm_kernel(const float* __restrict__ A,
                                                   const unsigned short* __restrict__ Whi,
                                                   const unsigned short* __restrict__ Wlo,
                                                   const float* __restrict__ bias,
                                                   float* __restrict__ C,
                                                   float* __restrict__ stats) {
  __shared__ float bsum[128];
  __shared__ float bsq[128];
  const int t = threadIdx.x;
  const int lane = t & 63;
  const int wv = t >> 6;
  if (STATS) {
    if (t < 128) { bsum[t] = 0.f; bsq[t] = 0.f; }
    __syncthreads();
  }

  const size_t strip = (size_t)blockIdx.x * 64 + wv * 16;      // 16-row strip base
  const size_t rowA = strip + (lane & 15);                     // A-frag row
  const int kb = (lane >> 4) << 3;                             // A/B-frag k sub-offset
  const float* Arow = A + rowA * 128 + kb;

  const short8* Bh = (const short8*)Whi;
  const short8* Bl = (const short8*)Wlo;

  f32x4 acc[8] = {};

#pragma unroll
  for (int ks = 0; ks < 4; ++ks) {
    f32x4 a0 = *(const f32x4*)(Arow + ks * 32);
    f32x4 a1 = *(const f32x4*)(Arow + ks * 32 + 4);
    short8 ah, al;
#pragma unroll
    for (int j = 0; j < 8; ++j) {
      float f = (j < 4) ? a0[j] : a1[j - 4];
      unsigned short h = f2bf(f);
      ah[j] = (short)h;
      al[j] = (short)f2bf(f - bf2f(h));
    }
#pragma unroll
    for (int ct = 0; ct < 8; ++ct) {
      const int idx = (ct * 4 + ks) * 64 + lane;
      short8 wh = Bh[idx];
      short8 wl = Bl[idx];
      acc[ct] = __builtin_amdgcn_mfma_f32_16x16x32_bf16(ah, wh, acc[ct], 0, 0, 0);
      acc[ct] = __builtin_amdgcn_mfma_f32_16x16x32_bf16(al, wh, acc[ct], 0, 0, 0);
      acc[ct] = __builtin_amdgcn_mfma_f32_16x16x32_bf16(ah, wl, acc[ct], 0, 0, 0);
    }
  }

  // epilogue: D row = (lane>>4)*4 + j, col = ct*16 + (lane&15)
  const int cbase = lane & 15;
  const size_t rowD = strip + ((lane >> 4) << 2);
#pragma unroll
  for (int ct = 0; ct < 8; ++ct) {
    const int c = ct * 16 + cbase;
    const float bc = bias[c];
    float s = 0.f, q = 0.f;
#pragma unroll
    for (int j = 0; j < 4; ++j) {
      float v = fmaxf(acc[ct][j] + bc, 0.f);
      C[(rowD + j) * 128 + c] = v;
      s += v;
      q += v * v;
    }
    if (STATS) {
      atomicAdd(&bsum[c], s);
      atomicAdd(&bsq[c], q);
    }
  }

  if (STATS) {
    __syncthreads();
    if (t < 128) {
      atomicAdd(&stats[t], bsum[t]);
      atomicAdd(&stats[128 + t], bsq[t]);
    }
  }
}

// ================================================================ BN apply + segment_max pool
__global__ __launch_bounds__(256) void bn_pool_kernel(float* __restrict__ h,
                                                      const float* __restrict__ stats,
                                                      const float* __restrict__ gamma,
                                                      const float* __restrict__ beta,
                                                      float* __restrict__ out, int layer) {
  __shared__ float red[256];
  const int g = blockIdx.x;
  const int t = threadIdx.x;
  const int f = t & 127, half = t >> 7;

  const float inv_n = 1.0f / (float)N_NODES_C;
  float mean = stats[f] * inv_n;
  float var = stats[128 + f] * inv_n - mean * mean;
  float sc = gamma[layer * 128 + f] * rsqrtf(var + BN_EPS_C);
  float sh = beta[layer * 128 + f] - mean * sc;

  float m = -3.4e38f;
  size_t base = ((size_t)g * 32 + half * 16) * 128 + f;
#pragma unroll
  for (int r = 0; r < 16; ++r) {
    float v = h[base + (size_t)r * 128];
    v = v * sc + sh;
    h[base + (size_t)r * 128] = v;
    m = fmaxf(m, v);
  }
  red[t] = m;
  __syncthreads();
  if (t < 128) out[(size_t)g * 640 + layer * 128 + f] = fmaxf(red[t], red[t + 128]);
}

// ================================================================ launch
extern "C" void kernel_launch(void* const* d_in, const int* in_sizes, int n_in,
                              void* d_out, int out_size, void* d_ws, size_t ws_size,
                              hipStream_t stream) {
  const float* x = (const float*)d_in[0];
  const int* ei = (const int*)d_in[1];
  const int* src = ei;
  const int* dst = ei + N_EDGES_C;
  const float* w0a = (const float*)d_in[3];
  const float* b0a = (const float*)d_in[4];
  const float* w0b = (const float*)d_in[5];
  const float* b0b = (const float*)d_in[6];
  const float* wa = (const float*)d_in[7];
  const float* ba = (const float*)d_in[8];
  const float* wb = (const float*)d_in[9];
  const float* bb = (const float*)d_in[10];
  const float* gamma = (const float*)d_in[11];
  const float* beta = (const float*)d_in[12];
  float* out = (float*)d_out;

  const size_t NNf = (size_t)N_NODES_C * 128;
  float* ws = (float*)d_ws;
  float* H = ws;
  float* AGG = ws + NNf;
  float* STATS = ws + 2 * NNf;
  int* cnt = (int*)(STATS + 256);
  int* rowstart = cnt + N_NODES_C;             // N_NODES+1 used (+3 pad)
  int* cursor = rowstart + N_NODES_C + 4;
  int* bsums = cursor + N_NODES_C;
  int* ebuf = bsums + 256;
  unsigned short* Whi = (unsigned short*)(((uintptr_t)(ebuf + N_EDGES_C) + 15) & ~(uintptr_t)15);
  unsigned short* Wlo = Whi + (size_t)10 * 16384;

  // ---------- weight split/pack + CSR build (edge_index fixed per launch)
  wsplit_kernel<<<80, 256, 0, stream>>>(w0a, w0b, wa, wb, Whi, Wlo);
  hipMemsetAsync(cnt, 0, N_NODES_C * sizeof(int), stream);
  hist_kernel<<<N_EDGES_C / 256, 256, 0, stream>>>(dst, cnt);
  scanA_kernel<<<256, 256, 0, stream>>>(cnt, rowstart, bsums);
  scanB_kernel<<<1, 256, 0, stream>>>(bsums);
  scanC_kernel<<<N_NODES_C / 256, 256, 0, stream>>>(rowstart, cursor, bsums);
  edge_bucket_kernel<<<N_EDGES_C / 256, 256, 0, stream>>>(src, dst, cursor, ebuf);

  const int GB = N_NODES_C / 64;  // gemm blocks

  // ---------- layer 0
  agg77_kernel<<<(N_NODES_C * 32) / 256, 256, 0, stream>>>(x, rowstart, ebuf, AGG);
  gemm_kernel<false><<<GB, 256, 0, stream>>>(AGG, Whi, Wlo, b0a, AGG, nullptr);  // mat 0, in-place
  hipMemsetAsync(STATS, 0, 256 * sizeof(float), stream);
  gemm_kernel<true><<<GB, 256, 0, stream>>>(AGG, Whi + 16384, Wlo + 16384, b0b, H, STATS);
  bn_pool_kernel<<<N_GRAPHS_C, 256, 0, stream>>>(H, STATS, gamma, beta, out, 0);

  // ---------- layers 1..4
  for (int i = 1; i < 5; ++i) {
    agg128_kernel<<<(N_NODES_C * 32) / 256, 256, 0, stream>>>((const float4*)H, rowstart, ebuf,
                                                              (float4*)AGG);
    const size_t mA = (size_t)(2 + (i - 1)) * 16384;
    const size_t mB = (size_t)(6 + (i - 1)) * 16384;
    gemm_kernel<false><<<GB, 256, 0, stream>>>(AGG, Whi + mA, Wlo + mA,
                                               ba + (size_t)(i - 1) * 128, AGG, nullptr);
    hipMemsetAsync(STATS, 0, 256 * sizeof(float), stream);
    gemm_kernel<true><<<GB, 256, 0, stream>>>(AGG, Whi + mB, Wlo + mB,
                                              bb + (size_t)(i - 1) * 128, H, STATS);
    bn_pool_kernel<<<N_GRAPHS_C, 256, 0, stream>>>(H, STATS, gamma, beta, out, i);
  }
}

// Round 5
// 1589.259 us; speedup vs baseline: 3.7316x; 1.2213x over previous
//
#include <hip/hip_runtime.h>
#include <cstdint>
#include <cstddef>

#define N_NODES_C 262144
#define N_EDGES_C 524288
#define N_GRAPHS_C 8192
#define BN_EPS_C 1e-5f

typedef short short8 __attribute__((ext_vector_type(8)));
typedef float f32x4 __attribute__((ext_vector_type(4)));

__device__ __forceinline__ unsigned short f2bf(float f) {
  unsigned int u = __float_as_uint(f);
  u += 0x7fffu + ((u >> 16) & 1u);   // RN-even
  return (unsigned short)(u >> 16);
}
__device__ __forceinline__ float bf2f(unsigned short h) {
  return __uint_as_float(((unsigned int)h) << 16);
}

// ================================================================ CSR build (once per launch)
__global__ __launch_bounds__(256) void hist_kernel(const int* __restrict__ dst, int* __restrict__ cnt) {
  int e = blockIdx.x * 256 + threadIdx.x;
  if (e < N_EDGES_C) atomicAdd(&cnt[dst[e]], 1);
}

__global__ __launch_bounds__(256) void scanA_kernel(const int* __restrict__ cnt,
                                                    int* __restrict__ rs, int* __restrict__ bsums) {
  __shared__ int lds[256];
  const int b = blockIdx.x, t = threadIdx.x;
  int4 v = ((const int4*)(cnt + b * 1024))[t];
  lds[t] = v.x + v.y + v.z + v.w;
  __syncthreads();
  for (int off = 1; off < 256; off <<= 1) {
    int add = (t >= off) ? lds[t - off] : 0;
    __syncthreads();
    lds[t] += add;
    __syncthreads();
  }
  int excl = (t > 0) ? lds[t - 1] : 0;
  if (t == 255) bsums[b] = lds[255];
  int4 o;
  o.x = excl; o.y = excl + v.x; o.z = excl + v.x + v.y; o.w = excl + v.x + v.y + v.z;
  ((int4*)(rs + b * 1024))[t] = o;
}

__global__ __launch_bounds__(256) void scanB_kernel(int* __restrict__ bsums) {
  __shared__ int lds[256];
  const int t = threadIdx.x;
  lds[t] = bsums[t];
  __syncthreads();
  for (int off = 1; off < 256; off <<= 1) {
    int add = (t >= off) ? lds[t - off] : 0;
    __syncthreads();
    lds[t] += add;
    __syncthreads();
  }
  bsums[t] = (t > 0) ? lds[t - 1] : 0;
}

__global__ __launch_bounds__(256) void scanC_kernel(int* __restrict__ rs, int* __restrict__ cursor,
                                                    const int* __restrict__ bsums) {
  int i = blockIdx.x * 256 + threadIdx.x;
  int v = rs[i] + bsums[i >> 10];
  rs[i] = v;
  cursor[i] = v;
  if (i == 0) rs[N_NODES_C] = N_EDGES_C;
}

__global__ __launch_bounds__(256) void edge_bucket_kernel(const int* __restrict__ src,
                                                          const int* __restrict__ dst,
                                                          int* __restrict__ cursor,
                                                          int* __restrict__ ebuf) {
  int e = blockIdx.x * 256 + threadIdx.x;
  if (e >= N_EDGES_C) return;
  int pos = atomicAdd(&cursor[dst[e]], 1);
  ebuf[pos] = src[e];
}

// ================================================================ gather aggregation
__global__ __launch_bounds__(256) void agg128_kernel(const float4* __restrict__ h4,
                                                     const int* __restrict__ rs,
                                                     const int* __restrict__ ebuf,
                                                     float4* __restrict__ agg4) {
  int idx = blockIdx.x * 256 + threadIdx.x;
  int n = idx >> 5, q = idx & 31;
  int s = rs[n], e = rs[n + 1];
  float4 v = h4[(size_t)n * 32 + q];
  for (int i = s; i < e; ++i) {
    int srcn = ebuf[i];
    float4 u = h4[(size_t)srcn * 32 + q];
    v.x += u.x; v.y += u.y; v.z += u.z; v.w += u.w;
  }
  agg4[(size_t)n * 32 + q] = v;
}

// layer-0 gather: reads x[N,77], writes zero-padded agg[N,128]
__global__ __launch_bounds__(256) void agg77_kernel(const float* __restrict__ x,
                                                    const int* __restrict__ rs,
                                                    const int* __restrict__ ebuf,
                                                    float* __restrict__ agg) {
  int idx = blockIdx.x * 256 + threadIdx.x;
  int n = idx >> 5, q = idx & 31;
  int s = rs[n], e = rs[n + 1];
  const size_t nb = (size_t)n * 77;
  float v0 = x[nb + q];
  float v1 = x[nb + q + 32];
  float v2 = (q < 13) ? x[nb + q + 64] : 0.f;
  for (int i = s; i < e; ++i) {
    const size_t sb = (size_t)ebuf[i] * 77;
    v0 += x[sb + q];
    v1 += x[sb + q + 32];
    if (q < 13) v2 += x[sb + q + 64];
  }
  const size_t ob = (size_t)n * 128;
  agg[ob + q] = v0;
  agg[ob + q + 32] = v1;
  agg[ob + q + 64] = (q < 13) ? v2 : 0.f;
  agg[ob + q + 96] = 0.f;
}

// ================================================================ weight split + frag-pack (once)
// Packed layout: [mat][ct(8)][ks(4)][lane(64)][j(8)]  (bf16 bits as ushort)
// frag element: W[k = ks*32 + (lane>>4)*8 + j][c = ct*16 + (lane&15)]
__global__ __launch_bounds__(256) void wsplit_kernel(const float* __restrict__ w0a,
                                                     const float* __restrict__ w0b,
                                                     const float* __restrict__ wa,
                                                     const float* __restrict__ wb,
                                                     unsigned short* __restrict__ Whi,
                                                     unsigned short* __restrict__ Wlo) {
  int tid = blockIdx.x * 256 + threadIdx.x;      // 20480 total
  int mat = tid >> 11;
  int rem = tid & 2047;
  int ct = rem >> 8;
  int ks = (rem >> 6) & 3;
  int lane = rem & 63;
  const int c = ct * 16 + (lane & 15);
  const size_t base = (size_t)mat * 16384 + (size_t)((ct * 4 + ks) * 64 + lane) * 8;
#pragma unroll
  for (int j = 0; j < 8; ++j) {
    int k = ks * 32 + ((lane >> 4) << 3) + j;
    float w;
    if (mat == 0)      w = (k < 77) ? w0a[k * 128 + c] : 0.f;
    else if (mat == 1) w = w0b[k * 128 + c];
    else if (mat < 6)  w = wa[(size_t)(mat - 2) * 16384 + k * 128 + c];
    else               w = wb[(size_t)(mat - 6) * 16384 + k * 128 + c];
    unsigned short h = f2bf(w);
    Whi[base + j] = h;
    Wlo[base + j] = f2bf(w - bf2f(h));
  }
}

// ================================================================ MFMA GEMM (bf16 hi/lo x3), LDS-staged W
// C[N,128] = relu(A[N,128] @ W + bias). 256 thr = 4 waves.
// Persistent-ish: grid 512 blocks (2/CU), each block owns 512 rows = 4 strips of 128;
// per strip each wave computes 2 row-tiles (32 rows). W (hi+lo, 64 KB) staged in LDS once.
// In-place safe: waves read & write only their own rows, stores after all loads of strip.
template <bool STATS>
__global__ __launch_bounds__(256) void gemm_kernel(const float* __restrict__ A,
                                                   const unsigned short* __restrict__ Whi,
                                                   const unsigned short* __restrict__ Wlo,
                                                   const float* __restrict__ bias,
                                                   float* __restrict__ C,
                                                   float* __restrict__ stats) {
  __shared__ int4 sW[4096];          // [0..2047]=hi, [2048..4095]=lo  (64 KB)
  __shared__ float bsum[128];
  __shared__ float bsq[128];

  const int t = threadIdx.x;
  const int lane = t & 63;
  const int wv = t >> 6;

  const int4* WhG = (const int4*)Whi;
  const int4* WlG = (const int4*)Wlo;
#pragma unroll
  for (int i = 0; i < 8; ++i) sW[t + i * 256] = WhG[t + i * 256];
#pragma unroll
  for (int i = 0; i < 8; ++i) sW[2048 + t + i * 256] = WlG[t + i * 256];
  __syncthreads();
  const short8* sWh = (const short8*)sW;
  const short8* sWl = (const short8*)(sW + 2048);

  const int cbase = lane & 15;
  const int kb = (lane >> 4) << 3;

  float bc[8];
#pragma unroll
  for (int ct = 0; ct < 8; ++ct) bc[ct] = bias[ct * 16 + cbase];

  float ssum[8] = {}, ssq[8] = {};   // per-thread BN partials (summed over strips+tiles)

  for (int sblk = 0; sblk < 4; ++sblk) {
    const size_t strip = (size_t)blockIdx.x * 512 + sblk * 128 + wv * 32;
    const float* Ar0 = A + (strip + cbase) * 128 + kb;
    const float* Ar1 = Ar0 + 16 * 128;

    f32x4 acc[2][8] = {};

#pragma unroll
    for (int ks = 0; ks < 4; ++ks) {
      f32x4 a00 = *(const f32x4*)(Ar0 + ks * 32);
      f32x4 a01 = *(const f32x4*)(Ar0 + ks * 32 + 4);
      f32x4 a10 = *(const f32x4*)(Ar1 + ks * 32);
      f32x4 a11 = *(const f32x4*)(Ar1 + ks * 32 + 4);
      short8 ah0, al0, ah1, al1;
#pragma unroll
      for (int j = 0; j < 8; ++j) {
        float f0 = (j < 4) ? a00[j] : a01[j - 4];
        unsigned short h0 = f2bf(f0);
        ah0[j] = (short)h0;
        al0[j] = (short)f2bf(f0 - bf2f(h0));
        float f1 = (j < 4) ? a10[j] : a11[j - 4];
        unsigned short h1 = f2bf(f1);
        ah1[j] = (short)h1;
        al1[j] = (short)f2bf(f1 - bf2f(h1));
      }
#pragma unroll
      for (int ct = 0; ct < 8; ++ct) {
        const int idx = (ct * 4 + ks) * 64 + lane;
        short8 wh = sWh[idx];
        short8 wl = sWl[idx];
        acc[0][ct] = __builtin_amdgcn_mfma_f32_16x16x32_bf16(ah0, wh, acc[0][ct], 0, 0, 0);
        acc[0][ct] = __builtin_amdgcn_mfma_f32_16x16x32_bf16(al0, wh, acc[0][ct], 0, 0, 0);
        acc[0][ct] = __builtin_amdgcn_mfma_f32_16x16x32_bf16(ah0, wl, acc[0][ct], 0, 0, 0);
        acc[1][ct] = __builtin_amdgcn_mfma_f32_16x16x32_bf16(ah1, wh, acc[1][ct], 0, 0, 0);
        acc[1][ct] = __builtin_amdgcn_mfma_f32_16x16x32_bf16(al1, wh, acc[1][ct], 0, 0, 0);
        acc[1][ct] = __builtin_amdgcn_mfma_f32_16x16x32_bf16(ah1, wl, acc[1][ct], 0, 0, 0);
      }
    }

    // epilogue: D row = tile*16 + (lane>>4)*4 + j, col = ct*16 + (lane&15)
#pragma unroll
    for (int tile = 0; tile < 2; ++tile) {
      const size_t rowD = strip + tile * 16 + ((lane >> 4) << 2);
#pragma unroll
      for (int ct = 0; ct < 8; ++ct) {
        const int c = ct * 16 + cbase;
#pragma unroll
        for (int j = 0; j < 4; ++j) {
          float v = fmaxf(acc[tile][ct][j] + bc[ct], 0.f);
          C[(rowD + j) * 128 + c] = v;
          if (STATS) { ssum[ct] += v; ssq[ct] += v * v; }
        }
      }
    }
  }

  if (STATS) {
    if (t < 128) { bsum[t] = 0.f; bsq[t] = 0.f; }
    __syncthreads();
#pragma unroll
    for (int ct = 0; ct < 8; ++ct) {
      const int c = ct * 16 + cbase;
      atomicAdd(&bsum[c], ssum[ct]);
      atomicAdd(&bsq[c], ssq[ct]);
    }
    __syncthreads();
    if (t < 128) {
      atomicAdd(&stats[t], bsum[t]);
      atomicAdd(&stats[128 + t], bsq[t]);
    }
  }
}

// ================================================================ BN apply + segment_max pool
__global__ __launch_bounds__(256) void bn_pool_kernel(float* __restrict__ h,
                                                      const float* __restrict__ stats,
                                                      const float* __restrict__ gamma,
                                                      const float* __restrict__ beta,
                                                      float* __restrict__ out, int layer) {
  __shared__ float red[256];
  const int g = blockIdx.x;
  const int t = threadIdx.x;
  const int f = t & 127, half = t >> 7;

  const float inv_n = 1.0f / (float)N_NODES_C;
  float mean = stats[f] * inv_n;
  float var = stats[128 + f] * inv_n - mean * mean;
  float sc = gamma[layer * 128 + f] * rsqrtf(var + BN_EPS_C);
  float sh = beta[layer * 128 + f] - mean * sc;

  float m = -3.4e38f;
  size_t base = ((size_t)g * 32 + half * 16) * 128 + f;
#pragma unroll
  for (int r = 0; r < 16; ++r) {
    float v = h[base + (size_t)r * 128];
    v = v * sc + sh;
    h[base + (size_t)r * 128] = v;
    m = fmaxf(m, v);
  }
  red[t] = m;
  __syncthreads();
  if (t < 128) out[(size_t)g * 640 + layer * 128 + f] = fmaxf(red[t], red[t + 128]);
}

// ================================================================ launch
extern "C" void kernel_launch(void* const* d_in, const int* in_sizes, int n_in,
                              void* d_out, int out_size, void* d_ws, size_t ws_size,
                              hipStream_t stream) {
  const float* x = (const float*)d_in[0];
  const int* ei = (const int*)d_in[1];
  const int* src = ei;
  const int* dst = ei + N_EDGES_C;
  const float* w0a = (const float*)d_in[3];
  const float* b0a = (const float*)d_in[4];
  const float* w0b = (const float*)d_in[5];
  const float* b0b = (const float*)d_in[6];
  const float* wa = (const float*)d_in[7];
  const float* ba = (const float*)d_in[8];
  const float* wb = (const float*)d_in[9];
  const float* bb = (const float*)d_in[10];
  const float* gamma = (const float*)d_in[11];
  const float* beta = (const float*)d_in[12];
  float* out = (float*)d_out;

  const size_t NNf = (size_t)N_NODES_C * 128;
  float* ws = (float*)d_ws;
  float* H = ws;
  float* AGG = ws + NNf;
  float* STATS = ws + 2 * NNf;
  int* cnt = (int*)(STATS + 256);
  int* rowstart = cnt + N_NODES_C;
  int* cursor = rowstart + N_NODES_C + 4;
  int* bsums = cursor + N_NODES_C;
  int* ebuf = bsums + 256;
  unsigned short* Whi = (unsigned short*)(((uintptr_t)(ebuf + N_EDGES_C) + 15) & ~(uintptr_t)15);
  unsigned short* Wlo = Whi + (size_t)10 * 16384;

  // ---------- weight split/pack + CSR build (edge_index fixed per launch)
  wsplit_kernel<<<80, 256, 0, stream>>>(w0a, w0b, wa, wb, Whi, Wlo);
  hipMemsetAsync(cnt, 0, N_NODES_C * sizeof(int), stream);
  hist_kernel<<<N_EDGES_C / 256, 256, 0, stream>>>(dst, cnt);
  scanA_kernel<<<256, 256, 0, stream>>>(cnt, rowstart, bsums);
  scanB_kernel<<<1, 256, 0, stream>>>(bsums);
  scanC_kernel<<<N_NODES_C / 256, 256, 0, stream>>>(rowstart, cursor, bsums);
  edge_bucket_kernel<<<N_EDGES_C / 256, 256, 0, stream>>>(src, dst, cursor, ebuf);

  const int GB = N_NODES_C / 512;  // 512 gemm blocks (2 per CU), 512 rows each

  // ---------- layer 0
  agg77_kernel<<<(N_NODES_C * 32) / 256, 256, 0, stream>>>(x, rowstart, ebuf, AGG);
  gemm_kernel<false><<<GB, 256, 0, stream>>>(AGG, Whi, Wlo, b0a, AGG, nullptr);  // mat 0, in-place
  hipMemsetAsync(STATS, 0, 256 * sizeof(float), stream);
  gemm_kernel<true><<<GB, 256, 0, stream>>>(AGG, Whi + 16384, Wlo + 16384, b0b, H, STATS);
  bn_pool_kernel<<<N_GRAPHS_C, 256, 0, stream>>>(H, STATS, gamma, beta, out, 0);

  // ---------- layers 1..4
  for (int i = 1; i < 5; ++i) {
    agg128_kernel<<<(N_NODES_C * 32) / 256, 256, 0, stream>>>((const float4*)H, rowstart, ebuf,
                                                              (float4*)AGG);
    const size_t mA = (size_t)(2 + (i - 1)) * 16384;
    const size_t mB = (size_t)(6 + (i - 1)) * 16384;
    gemm_kernel<false><<<GB, 256, 0, stream>>>(AGG, Whi + mA, Wlo + mA,
                                               ba + (size_t)(i - 1) * 128, AGG, nullptr);
    hipMemsetAsync(STATS, 0, 256 * sizeof(float), stream);
    gemm_kernel<true><<<GB, 256, 0, stream>>>(AGG, Whi + mB, Wlo + mB,
                                              bb + (size_t)(i - 1) * 128, H, STATS);
    bn_pool_kernel<<<N_GRAPHS_C, 256, 0, stream>>>(H, STATS, gamma, beta, out, i);
  }
}